// Round 12
// baseline (78.401 us; speedup 1.0000x reference)
//
#include <hip/hip_runtime.h>
#include <hip/hip_bf16.h>
#include <math.h>

#define NN 512
#define L2E 1.44269504089f
typedef __attribute__((ext_vector_type(4))) float f32x4;
typedef _Float16 h2v __attribute__((ext_vector_type(2)));
typedef _Float16 h8  __attribute__((ext_vector_type(8)));

// ws float offsets
#define OFF_XLI1  0u         // f16 xl interleaved: ushort[inst][jb8][q8][j64][d8]
#define OFF_XRH1  262144u    // f16 xr rows: ushort[inst][row512][d64]
#define OFF_VV1   524288u    // f32 [inst][512]
#define OFF_SAH1  532480u    // f16 [br][64]
#define OFF_SAH2  532544u    // f16 [br][64]
#define OFF_XLTF1 532608u    // f16 xl transposed [inst][d64][j512]
#define OFF_XLI2  794752u
#define OFF_XRH2  1056896u
#define OFF_XLTF2 1319040u
#define OFF_VV2   1581184u
#define OFF_POOL  1589376u   // f32 [inst16][ib32][64]
#define OFF_W2T   1622144u   // f16 W2^T [br][mat2][dout64][k64]

__device__ __forceinline__ float dterm(unsigned xr2, unsigned xl2, unsigned sa2, float acc)
{
#if __has_builtin(__builtin_amdgcn_fdot2)
    h2v z = __builtin_bit_cast(h2v, xr2) + __builtin_bit_cast(h2v, xl2);   // v_pk_add_f16
    unsigned az = __builtin_bit_cast(unsigned, z) & 0x7FFF7FFFu;           // dual abs
    return __builtin_amdgcn_fdot2(__builtin_bit_cast(h2v, az),
                                  __builtin_bit_cast(h2v, sa2), acc, false);
#else
    h2v z = __builtin_bit_cast(h2v, xr2) + __builtin_bit_cast(h2v, xl2);
    h2v s = __builtin_bit_cast(h2v, sa2);
    acc = fmaf((float)s[0], fabsf((float)z[0]), acc);
    return fmaf((float)s[1], fabsf((float)z[1]), acc);
#endif
}

__device__ __forceinline__ float qdot(unsigned hp, unsigned wp, float acc)
{
#if __has_builtin(__builtin_amdgcn_fdot2)
    return __builtin_amdgcn_fdot2(__builtin_bit_cast(h2v, hp),
                                  __builtin_bit_cast(h2v, wp), acc, false);
#else
    h2v h = __builtin_bit_cast(h2v, hp), w = __builtin_bit_cast(h2v, wp);
    acc = fmaf((float)h[0], (float)w[0], acc);
    return fmaf((float)h[1], (float)w[1], acc);
#endif
}

// ---------------- layer-1 GEMM (K=128) + v/sa layouts + SAH2/W2T prep ----------------
__global__ __launch_bounds__(256) void kpre(
    const float* __restrict__ src,
    const float* __restrict__ p1_Wl, const float* __restrict__ p1_Wr, const float* __restrict__ p1_a,
    const float* __restrict__ v1_Wl, const float* __restrict__ v1_Wr, const float* __restrict__ v1_a,
    const float* __restrict__ p2_Wl, const float* __restrict__ p2_Wr, const float* __restrict__ p2_a,
    const float* __restrict__ v2_Wl, const float* __restrict__ v2_Wr, const float* __restrict__ v2_a,
    float* __restrict__ ws)
{
    const int K = 128;
    __shared__ float xs[16 * 128];
    const int rb   = blockIdx.x;   // 0..31 : 16-row block
    const int inst = blockIdx.y;   // 0..15 (br*8 + batch)
    const int br   = inst >> 3;
    const int tid  = threadIdx.x;
    const int d = tid & 63, ig = tid >> 6;
    const float* Wl = br ? v1_Wl : p1_Wl;
    const float* Wr = br ? v1_Wr : p1_Wr;
    const float* av = br ? v1_a  : p1_a;
    const float* sp = src + (size_t)(inst & 7) * NN * K + (size_t)rb * 16 * K;

    for (int i = tid; i < 4 * K; i += 256) ((float4*)xs)[i] = ((const float4*)sp)[i];
    __syncthreads();

    float accl[4] = {0.f,0.f,0.f,0.f}, accr[4] = {0.f,0.f,0.f,0.f};
#pragma unroll 4
    for (int k4 = 0; k4 < K / 4; ++k4) {
        float xcv[4][4];
#pragma unroll
        for (int rr = 0; rr < 4; ++rr) {
            float4 v = ((const float4*)xs)[(ig * 4 + rr) * (K / 4) + k4];
            xcv[rr][0] = v.x; xcv[rr][1] = v.y; xcv[rr][2] = v.z; xcv[rr][3] = v.w;
        }
#pragma unroll
        for (int e = 0; e < 4; ++e) {
            float wl = Wl[(k4 * 4 + e) * 64 + d];   // coalesced, L1/L2-hot
            float wr = Wr[(k4 * 4 + e) * 64 + d];
#pragma unroll
            for (int rr = 0; rr < 4; ++rr) {
                accl[rr] = fmaf(xcv[rr][e], wl, accl[rr]);
                accr[rr] = fmaf(xcv[rr][e], wr, accr[rr]);
            }
        }
    }

    float aval = av[d];
    unsigned short* XLI  = (unsigned short*)(ws + OFF_XLI1);
    unsigned short* XRH  = (unsigned short*)(ws + OFF_XRH1);
    unsigned short* SAH  = (unsigned short*)(ws + OFF_SAH1);
    unsigned short* SAH2 = (unsigned short*)(ws + OFF_SAH2);
    unsigned short* XLTF = (unsigned short*)(ws + OFF_XLTF1);
    float* VV = ws + OFF_VV1;
#pragma unroll
    for (int rr = 0; rr < 4; ++rr) {
        int row = rb * 16 + ig * 4 + rr;
        XRH[(size_t)(inst * NN + row) * 64 + d] =
            __builtin_bit_cast(unsigned short, (_Float16)accr[rr]);
        XLI[((((size_t)inst * 8 + (row >> 6)) * 8 + (d >> 3)) * 64 + (row & 63)) * 8 + (d & 7)] =
            __builtin_bit_cast(unsigned short, (_Float16)accl[rr]);
        XLTF[(size_t)(inst * 64 + d) * NN + row] =
            __builtin_bit_cast(unsigned short, (_Float16)accl[rr]);
        float pv = aval * accl[rr];
#pragma unroll
        for (int mm = 32; mm > 0; mm >>= 1) pv += __shfl_xor(pv, mm, 64);
        if (d == 0) VV[inst * NN + row] = 0.6f * L2E * pv;   // log2e folded
    }
    if (rb == 0 && (inst & 7) == 0) {
        if (ig == 0) {
            SAH[br * 64 + d]  = __builtin_bit_cast(unsigned short, (_Float16)(0.4f * L2E * av[d]));
            SAH2[br * 64 + d] = __builtin_bit_cast(unsigned short,
                                  (_Float16)(0.4f * L2E * (br ? v2_a : p2_a)[d]));
        }
        // W2^T f16 prep: [mat][dout][k] so kattn's tail loads are k-contiguous uint4
        const float* W2l = br ? v2_Wl : p2_Wl;
        const float* W2r = br ? v2_Wr : p2_Wr;
        unsigned short* W2T = (unsigned short*)(ws + OFF_W2T) + br * 8192;
        for (int idx = tid; idx < 4096; idx += 256) {
            int k = idx >> 6, dc = idx & 63;             // coalesced reads
            W2T[dc * 64 + k]        = __builtin_bit_cast(unsigned short, (_Float16)W2l[idx]);
            W2T[4096 + dc * 64 + k] = __builtin_bit_cast(unsigned short, (_Float16)W2r[idx]);
        }
    }
}

// ------- fused attention; LAYER1 tail = fdot2 layer-2 pre-GEMM; LAYER2 tail = pool partial -------
template<int LAYER>
__global__ __launch_bounds__(512, 4) void kattn(
    const unsigned short* __restrict__ XLI, const unsigned short* __restrict__ XRH,
    const float* __restrict__ VV, const unsigned short* __restrict__ SAH,
    const unsigned short* __restrict__ XLTF,
    const float* __restrict__ b0, const float* __restrict__ b1,
    const unsigned short* __restrict__ W2T,
    const float* __restrict__ a20, const float* __restrict__ a21,
    unsigned short* __restrict__ XLI2, unsigned short* __restrict__ XRH2,
    unsigned short* __restrict__ XLTF2, float* __restrict__ VV2,
    float* __restrict__ Hout)
{
    __shared__ unsigned short pbuf[8][1024];   // per-wave p (f16), 16 KB; reused as h1h
    __shared__ float pout[8][1056];            // partial outs [w][i][66], 33 KB
    __shared__ unsigned short xr_s[16 * 64];   // 16 xr rows f16 (2 KB); reused as poolbuf
    __shared__ unsigned short sa_s[64];

    const int ib   = blockIdx.x;        // 0..31 : 16 i-rows
    const int inst = blockIdx.y;        // 0..15
    const int br   = inst >> 3;
    const int tid  = threadIdx.x;
    const int lane = tid & 63;
    const int w    = __builtin_amdgcn_readfirstlane(tid >> 6);   // wave id 0..7
    const float* VVi = VV + inst * NN;
    const unsigned short* XLTFi = XLTF + (size_t)inst * 64 * NN;
    const float* bias = br ? b1 : b0;

    // stage xr rows + sa once
    {
        const unsigned short* XRHp = XRH + ((size_t)inst * NN + ib * 16) * 64;
        if (tid < 128) ((uint4*)xr_s)[tid] = ((const uint4*)XRHp)[tid];
        if (tid < 8) ((uint4*)sa_s)[tid] = ((const uint4*)(SAH + br * 64))[tid];
    }

    // per-lane xl row (j = w*64+lane) as f16 pairs; 8 x uint4, coalesced
    unsigned xl2[32];
    {
        const uint4* xli = (const uint4*)XLI + ((size_t)inst * 8 + w) * 512;
#pragma unroll
        for (int q8 = 0; q8 < 8; ++q8) {
            uint4 v = xli[q8 * 64 + lane];
            xl2[q8*4+0] = v.x; xl2[q8*4+1] = v.y; xl2[q8*4+2] = v.z; xl2[q8*4+3] = v.w;
        }
    }
    float vj = VVi[w * 64 + lane];
    __syncthreads();   // b1: xr/sa staged

    // ---------------- scoring: e[16] via pk_add + and-abs + dot2 ----------------
    float e[16];
#pragma unroll
    for (int ii = 0; ii < 16; ++ii) e[ii] = 0.f;
    const uint4* xr4 = (const uint4*)xr_s;
    const uint4* sa4 = (const uint4*)sa_s;
#pragma unroll
    for (int q8 = 0; q8 < 8; ++q8) {
        uint4 s4 = sa4[q8];                    // broadcast b128
#pragma unroll
        for (int ii = 0; ii < 16; ++ii) {
            uint4 r4 = xr4[ii * 8 + q8];       // broadcast b128
            float t = dterm(r4.x, xl2[q8*4+0], s4.x, e[ii]);
            t = dterm(r4.y, xl2[q8*4+1], s4.y, t);
            t = dterm(r4.z, xl2[q8*4+2], s4.z, t);
            e[ii] = dterm(r4.w, xl2[q8*4+3], s4.w, t);
        }
    }

    // B-operand loads (L2-hot); latency hidden under p-split + pbuf round-trip
    float4 bv[8];
#pragma unroll
    for (int ks = 0; ks < 2; ++ks)
#pragma unroll
        for (int dt = 0; dt < 4; ++dt)
            bv[ks*4+dt] = *(const float4*)&XLTFi[(size_t)(dt * 16 + (lane & 15)) * NN +
                                                 w * 64 + ks * 32 + (lane >> 4) * 8];

    // ---------------- p = exp2 (f16), wave-private swizzled transpose in LDS ----------------
    unsigned short* phw = pbuf[w];
#pragma unroll
    for (int ii = 0; ii < 16; ++ii) {
        float p = exp2f(e[ii] + vj);           // p bounded ~2^10, f16-safe
        int idx = ii * 64 + (((lane >> 3) ^ (ii & 7)) << 3) + (lane & 7);
        phw[idx] = __builtin_bit_cast(unsigned short, (_Float16)p);
    }

    // ---------------- PV + den via f16 MFMA (wave-private A-frags) ----------------
    f32x4 accn[4] = {{0,0,0,0},{0,0,0,0},{0,0,0,0},{0,0,0,0}};
    f32x4 accd = {0, 0, 0, 0};
    const h8 ones = {(_Float16)1.f,(_Float16)1.f,(_Float16)1.f,(_Float16)1.f,
                     (_Float16)1.f,(_Float16)1.f,(_Float16)1.f,(_Float16)1.f};
#pragma unroll
    for (int ks = 0; ks < 2; ++ks) {
        int aidx = (lane & 15) * 64 + ((((ks << 2) + (lane >> 4)) ^ (lane & 7)) << 3);
        h8 a = *(const h8*)&phw[aidx];
#pragma unroll
        for (int dt = 0; dt < 4; ++dt)
            accn[dt] = __builtin_amdgcn_mfma_f32_16x16x32_f16(
                a, __builtin_bit_cast(h8, bv[ks*4+dt]), accn[dt], 0, 0, 0);
        accd = __builtin_amdgcn_mfma_f32_16x16x32_f16(a, ones, accd, 0, 0, 0);
    }

    // partial outs -> LDS: pout[w][i][66] (d 0..63, den at 64)
    float* pw = pout[w];
#pragma unroll
    for (int dt = 0; dt < 4; ++dt)
#pragma unroll
        for (int r = 0; r < 4; ++r)
            pw[((lane >> 4) * 4 + r) * 66 + dt * 16 + (lane & 15)] = accn[dt][r];
    if ((lane & 15) == 0) {
#pragma unroll
        for (int r = 0; r < 4; ++r)
            pw[((lane >> 4) * 4 + r) * 66 + 64] = accd[r];
    }
    __syncthreads();   // b2: partials visible (xr_s/pbuf dead after this)

    // ---------------- cross-wave reduction + epilogue ----------------
    const int i  = tid >> 5;         // 0..15
    const int dd = tid & 31;         // d pair
    float s0 = 0.f, s1 = 0.f, dn = 0.f;
#pragma unroll
    for (int ww = 0; ww < 8; ++ww) {
        const float* pb = &pout[ww][i * 66];
        float2 v = *(const float2*)&pb[dd * 2];
        s0 += v.x; s1 += v.y; dn += pb[64];
    }
    float inv = 1.f / dn;
    float v0 = s0 * inv + bias[dd * 2];
    float v1 = s1 * inv + bias[dd * 2 + 1];
    float t0 = 1.f - 2.f / (__expf(2.f * v0) + 1.f);   // tanh
    float t1 = 1.f - 2.f / (__expf(2.f * v1) + 1.f);

    if (LAYER == 1) {
        // ---- fused layer-2 pre-GEMM via packed f16 + fdot2 ----
        // h1h[row16][k2 32]: one packed f16 pair per thread, bank-conflict-free
        unsigned* h1h = (unsigned*)pbuf;               // 2 KB, pbuf dead
        h1h[i * 32 + dd] = (unsigned)__builtin_bit_cast(unsigned short, (_Float16)t0) |
                           ((unsigned)__builtin_bit_cast(unsigned short, (_Float16)t1) << 16);
        __syncthreads();   // b3: h1 staged

        const unsigned short* WT = W2T + br * 8192;    // [mat][dout][k] f16
        const float* a2 = br ? a21 : a20;
        const int r0w = w * 2;                         // this wave's 2 rows
        float accl2[2] = {0.f, 0.f}, accr2[2] = {0.f, 0.f};
        const uint4* h4 = (const uint4*)h1h;           // [row][8]
        const uint4* wl4 = (const uint4*)WT + lane * 8;         // dout = lane
        const uint4* wr4 = (const uint4*)(WT + 4096) + lane * 8;
#pragma unroll
        for (int q = 0; q < 8; ++q) {
            uint4 wl = wl4[q];                         // 8 k's f16 (16 VMEM total)
            uint4 wr = wr4[q];
#pragma unroll
            for (int rr = 0; rr < 2; ++rr) {
                uint4 h = h4[(r0w + rr) * 8 + q];      // wave-uniform b128 broadcast
                float al = accl2[rr], ar = accr2[rr];
                al = qdot(h.x, wl.x, al); ar = qdot(h.x, wr.x, ar);
                al = qdot(h.y, wl.y, al); ar = qdot(h.y, wr.y, ar);
                al = qdot(h.z, wl.z, al); ar = qdot(h.z, wr.z, ar);
                al = qdot(h.w, wl.w, al); ar = qdot(h.w, wr.w, ar);
                accl2[rr] = al; accr2[rr] = ar;
            }
        }
        float a2v = a2[lane];
#pragma unroll
        for (int rr = 0; rr < 2; ++rr) {
            int row = ib * 16 + r0w + rr;
            XRH2[(size_t)(inst * NN + row) * 64 + lane] =
                __builtin_bit_cast(unsigned short, (_Float16)accr2[rr]);
            XLI2[((((size_t)inst * 8 + (row >> 6)) * 8 + (lane >> 3)) * 64 + (row & 63)) * 8 + (lane & 7)] =
                __builtin_bit_cast(unsigned short, (_Float16)accl2[rr]);
            XLTF2[(size_t)(inst * 64 + lane) * NN + row] =
                __builtin_bit_cast(unsigned short, (_Float16)accl2[rr]);
            float pv = a2v * accl2[rr];
#pragma unroll
            for (int mm = 32; mm > 0; mm >>= 1) pv += __shfl_xor(pv, mm, 64);
            if (lane == 0) VV2[inst * NN + row] = 0.6f * L2E * pv;
        }
    } else {
        // ---- fused mean-pool partial (plain store; reduced by kfinal) ----
        float s0p = t0 + __shfl_xor(t0, 32, 64);
        float s1p = t1 + __shfl_xor(t1, 32, 64);
        float* poolbuf = (float*)xr_s;            // 512 f32 = 2 KB, xr_s is dead
        if (lane < 32) {
            poolbuf[w * 64 + dd * 2]     = s0p;
            poolbuf[w * 64 + dd * 2 + 1] = s1p;
        }
        __syncthreads();
        if (tid < 64) {
            float s = 0.f;
#pragma unroll
            for (int ww = 0; ww < 8; ++ww) s += poolbuf[ww * 64 + tid];
            Hout[((size_t)inst * 32 + ib) * 64 + tid] = s;   // pool partial slab
        }
    }
}

// ---------------- final: reduce 32 pool partials per instance -> d_out ----------------
__global__ __launch_bounds__(64) void kfinal(const float* __restrict__ pool,
                                             float* __restrict__ out)
{
    const int inst = blockIdx.x;     // 0..15
    const int d    = threadIdx.x;    // 0..63
    const float* p = pool + (size_t)inst * 32 * 64 + d;
    float s = 0.f;
#pragma unroll
    for (int ib = 0; ib < 32; ++ib) s += p[ib * 64];
    out[inst * 64 + d] = s * (1.f / NN);
}

extern "C" void kernel_launch(void* const* d_in, const int* in_sizes, int n_in,
                              void* d_out, int out_size, void* d_ws, size_t ws_size,
                              hipStream_t stream)
{
    (void)in_sizes; (void)n_in; (void)out_size; (void)ws_size;
    const float* feat  = (const float*)d_in[0];
    const float* p1_Wl = (const float*)d_in[1],  *p1_Wr = (const float*)d_in[2];
    const float* p1_a  = (const float*)d_in[3],  *p1_b  = (const float*)d_in[4];
    const float* p2_Wl = (const float*)d_in[5],  *p2_Wr = (const float*)d_in[6];
    const float* p2_a  = (const float*)d_in[7],  *p2_b  = (const float*)d_in[8];
    const float* v1_Wl = (const float*)d_in[9],  *v1_Wr = (const float*)d_in[10];
    const float* v1_a  = (const float*)d_in[11], *v1_b  = (const float*)d_in[12];
    const float* v2_Wl = (const float*)d_in[13], *v2_Wr = (const float*)d_in[14];
    const float* v2_a  = (const float*)d_in[15], *v2_b  = (const float*)d_in[16];

    float* ws = (float*)d_ws;
    unsigned short* XLI1  = (unsigned short*)(ws + OFF_XLI1);
    unsigned short* XRH1  = (unsigned short*)(ws + OFF_XRH1);
    unsigned short* SAH1  = (unsigned short*)(ws + OFF_SAH1);
    unsigned short* SAH2  = (unsigned short*)(ws + OFF_SAH2);
    unsigned short* XLTF1 = (unsigned short*)(ws + OFF_XLTF1);
    unsigned short* XLI2  = (unsigned short*)(ws + OFF_XLI2);
    unsigned short* XRH2  = (unsigned short*)(ws + OFF_XRH2);
    unsigned short* XLTF2 = (unsigned short*)(ws + OFF_XLTF2);
    unsigned short* W2T   = (unsigned short*)(ws + OFF_W2T);
    float* VV1  = ws + OFF_VV1;
    float* VV2  = ws + OFF_VV2;
    float* pool = ws + OFF_POOL;
    float* out  = (float*)d_out;

    // layer-1 GEMM + sa/W2T prep
    kpre<<<dim3(32, 16), 256, 0, stream>>>(feat,
                                           p1_Wl, p1_Wr, p1_a, v1_Wl, v1_Wr, v1_a,
                                           p2_Wl, p2_Wr, p2_a, v2_Wl, v2_Wr, v2_a, ws);
    // layer-1 attention + fused fdot2 layer-2 pre-GEMM
    kattn<1><<<dim3(32, 16), 512, 0, stream>>>(XLI1, XRH1, VV1, SAH1, XLTF1,
                                               p1_b, v1_b,
                                               W2T, p2_a, v2_a,
                                               XLI2, XRH2, XLTF2, VV2,
                                               nullptr);
    // layer-2 attention + fused mean-pool partials
    kattn<2><<<dim3(32, 16), 512, 0, stream>>>(XLI2, XRH2, VV2, SAH2, XLTF2,
                                               p2_b, v2_b,
                                               nullptr, nullptr, nullptr,
                                               nullptr, nullptr, nullptr, nullptr,
                                               pool);
    // final pool reduction (overwrites all of d_out deterministically)
    kfinal<<<16, 64, 0, stream>>>(pool, out);
}

// Round 13
// 68.190 us; speedup vs baseline: 1.1497x; 1.1497x over previous
//
#include <hip/hip_runtime.h>
#include <hip/hip_bf16.h>
#include <math.h>

#define NN 512
#define L2E 1.44269504089f
typedef __attribute__((ext_vector_type(4))) float f32x4;
typedef _Float16 h2v __attribute__((ext_vector_type(2)));
typedef _Float16 h8  __attribute__((ext_vector_type(8)));

// ws float offsets (single slab set, reused across layers)
#define OFF_XLI  0u         // f16 xl interleaved: ushort[inst][jb8][q8][j64][d8]
#define OFF_XRH  262144u    // f16 xr rows: ushort[inst][row512][d64]
#define OFF_VV   524288u    // f32 [inst][512]
#define OFF_SAH  532480u    // f16 [br][64]
#define OFF_XLTF 532608u    // f16 xl transposed [inst][d64][j512]
#define OFF_H1   794752u    // f32 H1 (16*512*64)
#define OFF_POOL 1319040u   // f32 pool partials [inst16][ib64][64]

__device__ __forceinline__ float dterm(unsigned xr2, unsigned xl2, unsigned sa2, float acc)
{
#if __has_builtin(__builtin_amdgcn_fdot2)
    h2v z = __builtin_bit_cast(h2v, xr2) + __builtin_bit_cast(h2v, xl2);   // v_pk_add_f16
    unsigned az = __builtin_bit_cast(unsigned, z) & 0x7FFF7FFFu;           // dual abs
    return __builtin_amdgcn_fdot2(__builtin_bit_cast(h2v, az),
                                  __builtin_bit_cast(h2v, sa2), acc, false);
#else
    h2v z = __builtin_bit_cast(h2v, xr2) + __builtin_bit_cast(h2v, xl2);
    h2v s = __builtin_bit_cast(h2v, sa2);
    acc = fmaf((float)s[0], fabsf((float)z[0]), acc);
    return fmaf((float)s[1], fabsf((float)z[1]), acc);
#endif
}

// ---------------- GEMM + v/sa + f16 interleaved / rows / transposed ----------------
template<int K>
__global__ __launch_bounds__(256) void kpre(
    const float* __restrict__ src, int srcPerInst,
    const float* __restrict__ Wl0, const float* __restrict__ Wr0, const float* __restrict__ a0,
    const float* __restrict__ Wl1, const float* __restrict__ Wr1, const float* __restrict__ a1,
    float* __restrict__ ws)
{
    __shared__ float xs[16 * K];
    const int rb   = blockIdx.x;   // 0..31 : 16-row block
    const int inst = blockIdx.y;   // 0..15 (br*8 + batch)
    const int br   = inst >> 3;
    const int tid  = threadIdx.x;
    const int d = tid & 63, ig = tid >> 6;
    const float* Wl = br ? Wl1 : Wl0;
    const float* Wr = br ? Wr1 : Wr0;
    const float* av = br ? a1  : a0;
    const float* sp = src + (size_t)(srcPerInst ? inst : (inst & 7)) * NN * K + (size_t)rb * 16 * K;

    for (int i = tid; i < 4 * K; i += 256) ((float4*)xs)[i] = ((const float4*)sp)[i];
    __syncthreads();

    float accl[4] = {0.f,0.f,0.f,0.f}, accr[4] = {0.f,0.f,0.f,0.f};
#pragma unroll 4
    for (int k4 = 0; k4 < K / 4; ++k4) {
        float xcv[4][4];
#pragma unroll
        for (int rr = 0; rr < 4; ++rr) {
            float4 v = ((const float4*)xs)[(ig * 4 + rr) * (K / 4) + k4];
            xcv[rr][0] = v.x; xcv[rr][1] = v.y; xcv[rr][2] = v.z; xcv[rr][3] = v.w;
        }
#pragma unroll
        for (int e = 0; e < 4; ++e) {
            float wl = Wl[(k4 * 4 + e) * 64 + d];   // coalesced, L1/L2-hot
            float wr = Wr[(k4 * 4 + e) * 64 + d];
#pragma unroll
            for (int rr = 0; rr < 4; ++rr) {
                accl[rr] = fmaf(xcv[rr][e], wl, accl[rr]);
                accr[rr] = fmaf(xcv[rr][e], wr, accr[rr]);
            }
        }
    }

    float aval = av[d];
    unsigned short* XLI  = (unsigned short*)(ws + OFF_XLI);
    unsigned short* XRH  = (unsigned short*)(ws + OFF_XRH);
    unsigned short* SAH  = (unsigned short*)(ws + OFF_SAH);
    unsigned short* XLTF = (unsigned short*)(ws + OFF_XLTF);
    float* VV = ws + OFF_VV;
#pragma unroll
    for (int rr = 0; rr < 4; ++rr) {
        int row = rb * 16 + ig * 4 + rr;
        XRH[(size_t)(inst * NN + row) * 64 + d] =
            __builtin_bit_cast(unsigned short, (_Float16)accr[rr]);
        XLI[((((size_t)inst * 8 + (row >> 6)) * 8 + (d >> 3)) * 64 + (row & 63)) * 8 + (d & 7)] =
            __builtin_bit_cast(unsigned short, (_Float16)accl[rr]);
        XLTF[(size_t)(inst * 64 + d) * NN + row] =
            __builtin_bit_cast(unsigned short, (_Float16)accl[rr]);
        float pv = aval * accl[rr];
#pragma unroll
        for (int mm = 32; mm > 0; mm >>= 1) pv += __shfl_xor(pv, mm, 64);
        if (d == 0) VV[inst * NN + row] = 0.6f * L2E * pv;   // log2e folded
    }
    if (rb == 0 && ig == 0 && (inst & 7) == 0)
        SAH[br * 64 + d] = __builtin_bit_cast(unsigned short, (_Float16)(0.4f * L2E * aval));
}

// ------- fused attention: 8 rows/block (grid 64x16) for 8 waves/SIMD occupancy -------
template<int LAYER>
__global__ __launch_bounds__(512, 4) void kattn(
    const float* __restrict__ ws,
    const float* __restrict__ b0, const float* __restrict__ b1,
    float* __restrict__ Hout)
{
    __shared__ unsigned short pbuf[8][1024];   // [w][row16*64] f16; rows 8-15 zeroed (16 KB)
    __shared__ float pout[8][528];             // [w][row8][66] (16.5 KB)
    __shared__ unsigned short xr_s[8 * 64];    // 8 xr rows f16 (1 KB); reused as poolbuf
    __shared__ unsigned short sa_s[64];

    const int ib   = blockIdx.x;        // 0..63 : 8 i-rows
    const int inst = blockIdx.y;        // 0..15
    const int br   = inst >> 3;
    const int tid  = threadIdx.x;
    const int lane = tid & 63;
    const int w    = __builtin_amdgcn_readfirstlane(tid >> 6);   // wave id 0..7
    const float* VV = ws + OFF_VV + inst * NN;
    const unsigned short* XLTF = (const unsigned short*)(ws + OFF_XLTF) + (size_t)inst * 64 * NN;
    const float* bias = br ? b1 : b0;

    // zero rows 8..15 of this wave's pbuf (A-frag upper half), once
    {
        uint4 z = {0u, 0u, 0u, 0u};
        ((uint4*)&pbuf[w][512])[lane] = z;
    }

    // stage xr rows (8 x 128B) + sa once
    {
        const unsigned short* XRH = (const unsigned short*)(ws + OFF_XRH) +
                                    ((size_t)inst * NN + ib * 8) * 64;
        if (tid < 64) ((uint4*)xr_s)[tid] = ((const uint4*)XRH)[tid];
        if (tid < 8)
            ((uint4*)sa_s)[tid] = ((const uint4*)((const unsigned short*)(ws + OFF_SAH) + br * 64))[tid];
    }

    // per-lane xl row (j = w*64+lane) as f16 pairs; 8 x uint4, coalesced
    unsigned xl2[32];
    {
        const uint4* xli = (const uint4*)(ws + OFF_XLI) + ((size_t)inst * 8 + w) * 512;
#pragma unroll
        for (int q8 = 0; q8 < 8; ++q8) {
            uint4 v = xli[q8 * 64 + lane];
            xl2[q8*4+0] = v.x; xl2[q8*4+1] = v.y; xl2[q8*4+2] = v.z; xl2[q8*4+3] = v.w;
        }
    }
    float vj = VV[w * 64 + lane];
    __syncthreads();   // b1: xr/sa staged

    // ---------------- scoring: e[8] via pk_add + and-abs + dot2 ----------------
    float e[8];
#pragma unroll
    for (int ii = 0; ii < 8; ++ii) e[ii] = 0.f;
    const uint4* xr4 = (const uint4*)xr_s;
    const uint4* sa4 = (const uint4*)sa_s;
#pragma unroll
    for (int q8 = 0; q8 < 8; ++q8) {
        uint4 s4 = sa4[q8];                    // broadcast b128
#pragma unroll
        for (int ii = 0; ii < 8; ++ii) {
            uint4 r4 = xr4[ii * 8 + q8];       // broadcast b128
            float t = dterm(r4.x, xl2[q8*4+0], s4.x, e[ii]);
            t = dterm(r4.y, xl2[q8*4+1], s4.y, t);
            t = dterm(r4.z, xl2[q8*4+2], s4.z, t);
            e[ii] = dterm(r4.w, xl2[q8*4+3], s4.w, t);
        }
    }

    // B-operand loads (L2-hot); latency hidden under p-split + pbuf round-trip
    float4 bv[8];
#pragma unroll
    for (int ks = 0; ks < 2; ++ks)
#pragma unroll
        for (int dt = 0; dt < 4; ++dt)
            bv[ks*4+dt] = *(const float4*)&XLTF[(size_t)(dt * 16 + (lane & 15)) * NN +
                                                w * 64 + ks * 32 + (lane >> 4) * 8];

    // ---------------- p = exp2 (f16), wave-private swizzled transpose in LDS ----------------
    unsigned short* phw = pbuf[w];
#pragma unroll
    for (int ii = 0; ii < 8; ++ii) {
        float p = exp2f(e[ii] + vj);           // p bounded ~2^10, f16-safe
        int idx = ii * 64 + (((lane >> 3) ^ (ii & 7)) << 3) + (lane & 7);
        phw[idx] = __builtin_bit_cast(unsigned short, (_Float16)p);
    }

    // ---------------- PV + den via f16 MFMA (wave-private A-frags; rows 8-15 zero) ----------------
    f32x4 accn[4] = {{0,0,0,0},{0,0,0,0},{0,0,0,0},{0,0,0,0}};
    f32x4 accd = {0, 0, 0, 0};
    const h8 ones = {(_Float16)1.f,(_Float16)1.f,(_Float16)1.f,(_Float16)1.f,
                     (_Float16)1.f,(_Float16)1.f,(_Float16)1.f,(_Float16)1.f};
#pragma unroll
    for (int ks = 0; ks < 2; ++ks) {
        int aidx = (lane & 15) * 64 + ((((ks << 2) + (lane >> 4)) ^ (lane & 7)) << 3);
        h8 a = *(const h8*)&phw[aidx];
#pragma unroll
        for (int dt = 0; dt < 4; ++dt)
            accn[dt] = __builtin_amdgcn_mfma_f32_16x16x32_f16(
                a, __builtin_bit_cast(h8, bv[ks*4+dt]), accn[dt], 0, 0, 0);
        accd = __builtin_amdgcn_mfma_f32_16x16x32_f16(a, ones, accd, 0, 0, 0);
    }

    // partial outs -> LDS: pout[w][row8][66] (rows 8-15 are zero: skip)
    {
        float* pw = pout[w];
#pragma unroll
        for (int r = 0; r < 4; ++r) {
            int row16 = (lane >> 4) * 4 + r;
            if (row16 < 8) {
#pragma unroll
                for (int dt = 0; dt < 4; ++dt)
                    pw[row16 * 66 + dt * 16 + (lane & 15)] = accn[dt][r];
                if ((lane & 15) == 0) pw[row16 * 66 + 64] = accd[r];
            }
        }
    }
    __syncthreads();   // b2: partials visible (xr_s/pbuf dead after this)

    // ---------------- cross-wave reduction + epilogue (threads 0..255: i = 0..7) ----------------
    const int i  = tid >> 5;         // row (0..7 valid for tid<256)
    const int dd = tid & 31;         // d pair
    float t0 = 0.f, t1 = 0.f;
    if (tid < 256) {
        float s0 = 0.f, s1 = 0.f, dn = 0.f;
#pragma unroll
        for (int ww = 0; ww < 8; ++ww) {
            const float* pb = &pout[ww][i * 66];
            float2 v = *(const float2*)&pb[dd * 2];
            s0 += v.x; s1 += v.y; dn += pb[64];
        }
        float inv = 1.f / dn;
        float v0 = s0 * inv + bias[dd * 2];
        float v1 = s1 * inv + bias[dd * 2 + 1];
        t0 = 1.f - 2.f / (__expf(2.f * v0) + 1.f);   // tanh
        t1 = 1.f - 2.f / (__expf(2.f * v1) + 1.f);
    }

    if (LAYER == 1) {
        if (tid < 256)
            *(float2*)&Hout[(size_t)(inst * NN + ib * 8 + i) * 64 + dd * 2] = make_float2(t0, t1);
    } else {
        // fused mean-pool partial: waves 0-3 pair-sum their 2 rows, block reduce, plain store
        float* poolbuf = (float*)xr_s;            // 256 f32 = 1 KB, xr_s is dead
        if (tid < 256) {
            float s0p = t0 + __shfl_xor(t0, 32, 64);
            float s1p = t1 + __shfl_xor(t1, 32, 64);
            if (lane < 32) {
                poolbuf[w * 64 + dd * 2]     = s0p;
                poolbuf[w * 64 + dd * 2 + 1] = s1p;
            }
        }
        __syncthreads();
        if (tid < 64) {
            float s = 0.f;
#pragma unroll
            for (int ww = 0; ww < 4; ++ww) s += poolbuf[ww * 64 + tid];
            Hout[((size_t)inst * 64 + ib) * 64 + tid] = s;   // pool partial slab
        }
    }
}

// ---------------- final: reduce 64 pool partials per instance -> d_out ----------------
__global__ __launch_bounds__(64) void kfinal(const float* __restrict__ pool,
                                             float* __restrict__ out)
{
    const int inst = blockIdx.x;     // 0..15
    const int d    = threadIdx.x;    // 0..63
    const float* p = pool + (size_t)inst * 64 * 64 + d;
    float s = 0.f;
#pragma unroll
    for (int ib = 0; ib < 64; ++ib) s += p[ib * 64];
    out[inst * 64 + d] = s * (1.f / NN);
}

extern "C" void kernel_launch(void* const* d_in, const int* in_sizes, int n_in,
                              void* d_out, int out_size, void* d_ws, size_t ws_size,
                              hipStream_t stream)
{
    (void)in_sizes; (void)n_in; (void)out_size; (void)ws_size;
    const float* feat  = (const float*)d_in[0];
    const float* p1_Wl = (const float*)d_in[1],  *p1_Wr = (const float*)d_in[2];
    const float* p1_a  = (const float*)d_in[3],  *p1_b  = (const float*)d_in[4];
    const float* p2_Wl = (const float*)d_in[5],  *p2_Wr = (const float*)d_in[6];
    const float* p2_a  = (const float*)d_in[7],  *p2_b  = (const float*)d_in[8];
    const float* v1_Wl = (const float*)d_in[9],  *v1_Wr = (const float*)d_in[10];
    const float* v1_a  = (const float*)d_in[11], *v1_b  = (const float*)d_in[12];
    const float* v2_Wl = (const float*)d_in[13], *v2_Wr = (const float*)d_in[14];
    const float* v2_a  = (const float*)d_in[15], *v2_b  = (const float*)d_in[16];

    float* ws = (float*)d_ws;
    float* H1 = ws + OFF_H1;
    float* pool = ws + OFF_POOL;
    float* out = (float*)d_out;

    // layer 1 (input: features, K=128)
    kpre<128><<<dim3(32, 16), 256, 0, stream>>>(feat, 0, p1_Wl, p1_Wr, p1_a,
                                                v1_Wl, v1_Wr, v1_a, ws);
    kattn<1><<<dim3(64, 16), 512, 0, stream>>>(ws, p1_b, v1_b, H1);
    // layer 2 (input: H1, K=64) + fused mean-pool partials
    kpre<64><<<dim3(32, 16), 256, 0, stream>>>(H1, 1, p2_Wl, p2_Wr, p2_a,
                                               v2_Wl, v2_Wr, v2_a, ws);
    kattn<2><<<dim3(64, 16), 512, 0, stream>>>(ws, p2_b, v2_b, pool);
    // final pool reduction (overwrites all of d_out deterministically)
    kfinal<<<16, 64, 0, stream>>>(pool, out);
}

// Round 14
// 66.927 us; speedup vs baseline: 1.1714x; 1.0189x over previous
//
#include <hip/hip_runtime.h>
#include <hip/hip_bf16.h>
#include <math.h>

#define NN 512
#define L2E 1.44269504089f
typedef __attribute__((ext_vector_type(4))) float f32x4;
typedef _Float16 h2v __attribute__((ext_vector_type(2)));
typedef _Float16 h8  __attribute__((ext_vector_type(8)));

// ws float offsets
#define OFF_XLI  0u         // f16 xl interleaved: ushort[inst][jb8][q8][j64][d8]
#define OFF_XRH  262144u    // f16 xr rows: ushort[inst][row512][d64]
#define OFF_VV   524288u    // f32 [inst][512]
#define OFF_SAH  532480u    // f16 [br][64]
#define OFF_XLTF 532608u    // f16 xl transposed [inst][d64][j512]
#define OFF_H1   794752u    // f32 H1 (16*512*64)
#define OFF_POOL 1319040u   // f32 pool partials [inst16][ib32][64]

__device__ __forceinline__ float dterm(unsigned xr2, unsigned xl2, unsigned sa2, float acc)
{
#if __has_builtin(__builtin_amdgcn_fdot2)
    h2v z = __builtin_bit_cast(h2v, xr2) + __builtin_bit_cast(h2v, xl2);   // v_pk_add_f16
    unsigned az = __builtin_bit_cast(unsigned, z) & 0x7FFF7FFFu;           // dual abs
    return __builtin_amdgcn_fdot2(__builtin_bit_cast(h2v, az),
                                  __builtin_bit_cast(h2v, sa2), acc, false);
#else
    h2v z = __builtin_bit_cast(h2v, xr2) + __builtin_bit_cast(h2v, xl2);
    h2v s = __builtin_bit_cast(h2v, sa2);
    acc = fmaf((float)s[0], fabsf((float)z[0]), acc);
    return fmaf((float)s[1], fabsf((float)z[1]), acc);
#endif
}

// ---------------- GEMM + v/sa + f16 interleaved / rows / transposed (R9 verbatim) ----------------
template<int K>
__global__ __launch_bounds__(256) void kpre(
    const float* __restrict__ src, int srcPerInst,
    const float* __restrict__ Wl0, const float* __restrict__ Wr0, const float* __restrict__ a0,
    const float* __restrict__ Wl1, const float* __restrict__ Wr1, const float* __restrict__ a1,
    float* __restrict__ ws)
{
    __shared__ float xs[16 * K];
    const int rb   = blockIdx.x;   // 0..31 : 16-row block
    const int inst = blockIdx.y;   // 0..15 (br*8 + batch)
    const int br   = inst >> 3;
    const int tid  = threadIdx.x;
    const int d = tid & 63, ig = tid >> 6;
    const float* Wl = br ? Wl1 : Wl0;
    const float* Wr = br ? Wr1 : Wr0;
    const float* av = br ? a1  : a0;
    const float* sp = src + (size_t)(srcPerInst ? inst : (inst & 7)) * NN * K + (size_t)rb * 16 * K;

    for (int i = tid; i < 4 * K; i += 256) ((float4*)xs)[i] = ((const float4*)sp)[i];
    __syncthreads();

    float accl[4] = {0.f,0.f,0.f,0.f}, accr[4] = {0.f,0.f,0.f,0.f};
#pragma unroll 4
    for (int k4 = 0; k4 < K / 4; ++k4) {
        float xcv[4][4];
#pragma unroll
        for (int rr = 0; rr < 4; ++rr) {
            float4 v = ((const float4*)xs)[(ig * 4 + rr) * (K / 4) + k4];
            xcv[rr][0] = v.x; xcv[rr][1] = v.y; xcv[rr][2] = v.z; xcv[rr][3] = v.w;
        }
#pragma unroll
        for (int e = 0; e < 4; ++e) {
            float wl = Wl[(k4 * 4 + e) * 64 + d];   // coalesced, L1/L2-hot
            float wr = Wr[(k4 * 4 + e) * 64 + d];
#pragma unroll
            for (int rr = 0; rr < 4; ++rr) {
                accl[rr] = fmaf(xcv[rr][e], wl, accl[rr]);
                accr[rr] = fmaf(xcv[rr][e], wr, accr[rr]);
            }
        }
    }

    float aval = av[d];
    unsigned short* XLI  = (unsigned short*)(ws + OFF_XLI);
    unsigned short* XRH  = (unsigned short*)(ws + OFF_XRH);
    unsigned short* SAH  = (unsigned short*)(ws + OFF_SAH);
    unsigned short* XLTF = (unsigned short*)(ws + OFF_XLTF);
    float* VV = ws + OFF_VV;
#pragma unroll
    for (int rr = 0; rr < 4; ++rr) {
        int row = rb * 16 + ig * 4 + rr;
        XRH[(size_t)(inst * NN + row) * 64 + d] =
            __builtin_bit_cast(unsigned short, (_Float16)accr[rr]);
        XLI[((((size_t)inst * 8 + (row >> 6)) * 8 + (d >> 3)) * 64 + (row & 63)) * 8 + (d & 7)] =
            __builtin_bit_cast(unsigned short, (_Float16)accl[rr]);
        XLTF[(size_t)(inst * 64 + d) * NN + row] =
            __builtin_bit_cast(unsigned short, (_Float16)accl[rr]);
        float pv = aval * accl[rr];
#pragma unroll
        for (int mm = 32; mm > 0; mm >>= 1) pv += __shfl_xor(pv, mm, 64);
        if (d == 0) VV[inst * NN + row] = 0.6f * L2E * pv;   // log2e folded
    }
    if (rb == 0 && ig == 0 && (inst & 7) == 0)
        SAH[br * 64 + d] = __builtin_bit_cast(unsigned short, (_Float16)(0.4f * L2E * aval));
}

// ------- fused attention: wave = (8 rows x 128 j) scoring to halve LDS broadcasts -------
template<int LAYER>
__global__ __launch_bounds__(512, 4) void kattn(
    const float* __restrict__ ws,
    const float* __restrict__ b0, const float* __restrict__ b1,
    float* __restrict__ Hout)
{
    __shared__ unsigned short pbuf[8][1024];   // [jg][row16 x 64j] f16 swizzled (16 KB)
    __shared__ float pout[8][1056];            // partial outs [w][i][66], 33 KB
    __shared__ unsigned short xr_s[16 * 64];   // 16 xr rows f16 (2 KB); reused as poolbuf
    __shared__ unsigned short sa_s[64];

    const int ib   = blockIdx.x;        // 0..31 : 16 i-rows
    const int inst = blockIdx.y;        // 0..15
    const int br   = inst >> 3;
    const int tid  = threadIdx.x;
    const int lane = tid & 63;
    const int w    = __builtin_amdgcn_readfirstlane(tid >> 6);   // wave id 0..7
    const int gr   = w >> 2;            // row group (rows gr*8 .. +8)
    const int gj   = w & 3;             // j group (j gj*128 .. +128)
    const int jba  = gj * 2;            // 64-j block of j_a = jba*64 + lane
    const int jbb  = gj * 2 + 1;        // 64-j block of j_b
    const float* VV = ws + OFF_VV + inst * NN;
    const unsigned short* XLTF = (const unsigned short*)(ws + OFF_XLTF) + (size_t)inst * 64 * NN;
    const float* bias = br ? b1 : b0;

    // stage xr rows + sa once
    {
        const unsigned short* XRH = (const unsigned short*)(ws + OFF_XRH) +
                                    ((size_t)inst * NN + ib * 16) * 64;
        if (tid < 128) ((uint4*)xr_s)[tid] = ((const uint4*)XRH)[tid];
        if (tid < 8)
            ((uint4*)sa_s)[tid] = ((const uint4*)((const unsigned short*)(ws + OFF_SAH) + br * 64))[tid];
    }

    // per-lane xl rows for j_a and j_b (both fully coalesced)
    unsigned xa[32], xb[32];
    {
        const uint4* xli = (const uint4*)(ws + OFF_XLI) + (size_t)inst * 8 * 512;
        const uint4* xla = xli + (size_t)jba * 512;
        const uint4* xlb = xli + (size_t)jbb * 512;
#pragma unroll
        for (int q8 = 0; q8 < 8; ++q8) {
            uint4 va = xla[q8 * 64 + lane];
            uint4 vb = xlb[q8 * 64 + lane];
            xa[q8*4+0] = va.x; xa[q8*4+1] = va.y; xa[q8*4+2] = va.z; xa[q8*4+3] = va.w;
            xb[q8*4+0] = vb.x; xb[q8*4+1] = vb.y; xb[q8*4+2] = vb.z; xb[q8*4+3] = vb.w;
        }
    }
    float vja = VV[jba * 64 + lane];
    float vjb = VV[jbb * 64 + lane];
    __syncthreads();   // b1: xr/sa staged

    // ---------------- scoring: 8 rows x 2 j per lane; xr/sa broadcasts amortized 2x ----------------
    float ea[8], eb[8];
#pragma unroll
    for (int ii = 0; ii < 8; ++ii) { ea[ii] = 0.f; eb[ii] = 0.f; }
    const uint4* xr4 = (const uint4*)xr_s;
    const uint4* sa4 = (const uint4*)sa_s;
#pragma unroll
    for (int q8 = 0; q8 < 8; ++q8) {
        uint4 s4 = sa4[q8];                            // broadcast b128
#pragma unroll
        for (int ii = 0; ii < 8; ++ii) {
            uint4 r4 = xr4[(gr * 8 + ii) * 8 + q8];    // broadcast b128 (8 rows, not 16)
            float ta = dterm(r4.x, xa[q8*4+0], s4.x, ea[ii]);
            float tb = dterm(r4.x, xb[q8*4+0], s4.x, eb[ii]);
            ta = dterm(r4.y, xa[q8*4+1], s4.y, ta);
            tb = dterm(r4.y, xb[q8*4+1], s4.y, tb);
            ta = dterm(r4.z, xa[q8*4+2], s4.z, ta);
            tb = dterm(r4.z, xb[q8*4+2], s4.z, tb);
            ea[ii] = dterm(r4.w, xa[q8*4+3], s4.w, ta);
            eb[ii] = dterm(r4.w, xb[q8*4+3], s4.w, tb);
        }
    }

    // B-operand loads (L2-hot); drain under the coming barrier
    float4 bv[8];
#pragma unroll
    for (int ks = 0; ks < 2; ++ks)
#pragma unroll
        for (int dt = 0; dt < 4; ++dt)
            bv[ks*4+dt] = *(const float4*)&XLTF[(size_t)(dt * 16 + (lane & 15)) * NN +
                                                w * 64 + ks * 32 + (lane >> 4) * 8];

    // ---------------- p = exp2 (f16) into pbuf[jba]/pbuf[jbb] (validated swizzle) ----------------
#pragma unroll
    for (int ii = 0; ii < 8; ++ii) {
        int row = gr * 8 + ii;
        float pa = exp2f(ea[ii] + vja);
        float pb = exp2f(eb[ii] + vjb);
        int idx = row * 64 + (((lane >> 3) ^ (row & 7)) << 3) + (lane & 7);
        pbuf[jba][idx] = __builtin_bit_cast(unsigned short, (_Float16)pa);
        pbuf[jbb][idx] = __builtin_bit_cast(unsigned short, (_Float16)pb);
    }
    __syncthreads();   // b_p: all p visible (pbuf no longer wave-private)

    // ---------------- PV + den via f16 MFMA (wave w consumes pbuf[w]; R9 verbatim) ----------------
    const unsigned short* phw = pbuf[w];
    f32x4 accn[4] = {{0,0,0,0},{0,0,0,0},{0,0,0,0},{0,0,0,0}};
    f32x4 accd = {0, 0, 0, 0};
    const h8 ones = {(_Float16)1.f,(_Float16)1.f,(_Float16)1.f,(_Float16)1.f,
                     (_Float16)1.f,(_Float16)1.f,(_Float16)1.f,(_Float16)1.f};
#pragma unroll
    for (int ks = 0; ks < 2; ++ks) {
        int aidx = (lane & 15) * 64 + ((((ks << 2) + (lane >> 4)) ^ (lane & 7)) << 3);
        h8 a = *(const h8*)&phw[aidx];
#pragma unroll
        for (int dt = 0; dt < 4; ++dt)
            accn[dt] = __builtin_amdgcn_mfma_f32_16x16x32_f16(
                a, __builtin_bit_cast(h8, bv[ks*4+dt]), accn[dt], 0, 0, 0);
        accd = __builtin_amdgcn_mfma_f32_16x16x32_f16(a, ones, accd, 0, 0, 0);
    }

    // partial outs -> LDS: pout[w][i][66] (d 0..63, den at 64)
    float* pw = pout[w];
#pragma unroll
    for (int dt = 0; dt < 4; ++dt)
#pragma unroll
        for (int r = 0; r < 4; ++r)
            pw[((lane >> 4) * 4 + r) * 66 + dt * 16 + (lane & 15)] = accn[dt][r];
    if ((lane & 15) == 0) {
#pragma unroll
        for (int r = 0; r < 4; ++r)
            pw[((lane >> 4) * 4 + r) * 66 + 64] = accd[r];
    }
    __syncthreads();   // b2: partials visible (xr_s/pbuf dead after this)

    // ---------------- cross-wave reduction + epilogue (R9 verbatim) ----------------
    const int i  = tid >> 5;         // 0..15
    const int dd = tid & 31;         // d pair
    float s0 = 0.f, s1 = 0.f, dn = 0.f;
#pragma unroll
    for (int ww = 0; ww < 8; ++ww) {
        const float* pb = &pout[ww][i * 66];
        float2 v = *(const float2*)&pb[dd * 2];
        s0 += v.x; s1 += v.y; dn += pb[64];
    }
    float inv = 1.f / dn;
    float v0 = s0 * inv + bias[dd * 2];
    float v1 = s1 * inv + bias[dd * 2 + 1];
    float t0 = 1.f - 2.f / (__expf(2.f * v0) + 1.f);   // tanh
    float t1 = 1.f - 2.f / (__expf(2.f * v1) + 1.f);

    if (LAYER == 1) {
        *(float2*)&Hout[(size_t)(inst * NN + ib * 16 + i) * 64 + dd * 2] = make_float2(t0, t1);
    } else {
        // fused mean-pool partial (plain store; reduced by kfinal)
        float s0p = t0 + __shfl_xor(t0, 32, 64);
        float s1p = t1 + __shfl_xor(t1, 32, 64);
        float* poolbuf = (float*)xr_s;            // 512 f32 = 2 KB, xr_s is dead
        if (lane < 32) {
            poolbuf[w * 64 + dd * 2]     = s0p;
            poolbuf[w * 64 + dd * 2 + 1] = s1p;
        }
        __syncthreads();
        if (tid < 64) {
            float s = 0.f;
#pragma unroll
            for (int ww = 0; ww < 8; ++ww) s += poolbuf[ww * 64 + tid];
            Hout[((size_t)inst * 32 + ib) * 64 + tid] = s;   // pool partial slab
        }
    }
}

// ---------------- final: reduce 32 pool partials per instance -> d_out ----------------
__global__ __launch_bounds__(64) void kfinal(const float* __restrict__ pool,
                                             float* __restrict__ out)
{
    const int inst = blockIdx.x;     // 0..15
    const int d    = threadIdx.x;    // 0..63
    const float* p = pool + (size_t)inst * 32 * 64 + d;
    float s = 0.f;
#pragma unroll
    for (int ib = 0; ib < 32; ++ib) s += p[ib * 64];
    out[inst * 64 + d] = s * (1.f / NN);
}

extern "C" void kernel_launch(void* const* d_in, const int* in_sizes, int n_in,
                              void* d_out, int out_size, void* d_ws, size_t ws_size,
                              hipStream_t stream)
{
    (void)in_sizes; (void)n_in; (void)out_size; (void)ws_size;
    const float* feat  = (const float*)d_in[0];
    const float* p1_Wl = (const float*)d_in[1],  *p1_Wr = (const float*)d_in[2];
    const float* p1_a  = (const float*)d_in[3],  *p1_b  = (const float*)d_in[4];
    const float* p2_Wl = (const float*)d_in[5],  *p2_Wr = (const float*)d_in[6];
    const float* p2_a  = (const float*)d_in[7],  *p2_b  = (const float*)d_in[8];
    const float* v1_Wl = (const float*)d_in[9],  *v1_Wr = (const float*)d_in[10];
    const float* v1_a  = (const float*)d_in[11], *v1_b  = (const float*)d_in[12];
    const float* v2_Wl = (const float*)d_in[13], *v2_Wr = (const float*)d_in[14];
    const float* v2_a  = (const float*)d_in[15], *v2_b  = (const float*)d_in[16];

    float* ws = (float*)d_ws;
    float* H1 = ws + OFF_H1;
    float* pool = ws + OFF_POOL;
    float* out = (float*)d_out;

    // layer 1 (input: features, K=128)
    kpre<128><<<dim3(32, 16), 256, 0, stream>>>(feat, 0, p1_Wl, p1_Wr, p1_a,
                                                v1_Wl, v1_Wr, v1_a, ws);
    kattn<1><<<dim3(32, 16), 512, 0, stream>>>(ws, p1_b, v1_b, H1);
    // layer 2 (input: H1, K=64) + fused mean-pool partials
    kpre<64><<<dim3(32, 16), 256, 0, stream>>>(H1, 1, p2_Wl, p2_Wr, p2_a,
                                               v2_Wl, v2_Wr, v2_a, ws);
    kattn<2><<<dim3(32, 16), 512, 0, stream>>>(ws, p2_b, v2_b, pool);
    // final pool reduction (overwrites all of d_out deterministically)
    kfinal<<<16, 64, 0, stream>>>(pool, out);
}